// Round 15
// baseline (263.372 us; speedup 1.0000x reference)
//
#include <hip/hip_runtime.h>
#include <stdint.h>

#define MB (1ull << 20)
typedef unsigned short u16;
typedef __attribute__((ext_vector_type(8))) short bf16x8;
typedef __attribute__((ext_vector_type(4))) float f32x4;

__device__ __forceinline__ float b2f(u16 u) {
  union { unsigned int i; float f; } c; c.i = ((unsigned int)u) << 16; return c.f;
}
__device__ __forceinline__ u16 f2b(float f) {
  union { float f; unsigned int i; } c; c.f = f;
  unsigned int r = c.i + 0x7fffu + ((c.i >> 16) & 1u);
  return (u16)(r >> 16);
}
__device__ __forceinline__ void gload16(const void* g, void* l) {
  __builtin_amdgcn_global_load_lds(
      (const __attribute__((address_space(1))) void*)g,
      (__attribute__((address_space(3))) void*)l, 16, 0, 0);
}

// ---------------- fused f32 -> bf16 convert ----------------
__global__ __launch_bounds__(256) void f2b_all(
    const float* __restrict__ x, const float* __restrict__ wq, const float* __restrict__ wk,
    const float* __restrict__ wv, const float* __restrict__ wo, const float* __restrict__ w1,
    const float* __restrict__ w2,
    u16* __restrict__ xb, u16* __restrict__ wqkvb, u16* __restrict__ wob,
    u16* __restrict__ w1b, u16* __restrict__ w2b)
{
  int bid = blockIdx.x;
  const float* src; u16* dst;
  if (bid < 4096)       { src = x;  dst = xb; }
  else if (bid < 5120)  { src = wq; dst = wqkvb;           bid -= 4096; }
  else if (bid < 6144)  { src = wk; dst = wqkvb + 1048576; bid -= 5120; }
  else if (bid < 7168)  { src = wv; dst = wqkvb + 2097152; bid -= 6144; }
  else if (bid < 8192)  { src = wo; dst = wob;             bid -= 7168; }
  else if (bid < 12288) { src = w1; dst = w1b;             bid -= 8192; }
  else                  { src = w2; dst = w2b;             bid -= 12288; }
  int i = (bid * 256 + threadIdx.x) * 4;
  float4 v = *(const float4*)(src + i);
  uint2 ov;
  ov.x = (unsigned)f2b(v.x) | ((unsigned)f2b(v.y) << 16);
  ov.y = (unsigned)f2b(v.z) | ((unsigned)f2b(v.w) << 16);
  *(uint2*)(dst + i) = ov;
}

// ---------------- RoPE cos/sin table ----------------
__global__ __launch_bounds__(256) void rope_tab_kernel(float2* __restrict__ tab) {
  int idx = blockIdx.x * 256 + threadIdx.x;
  int s = idx >> 5, j = idx & 31;
  float inv = exp2f(-(float)j * (13.287712379549449f / 32.0f));
  float sn, cs;
  sincosf((float)s * inv, &sn, &cs);
  tab[idx] = make_float2(cs, sn);
}

// ---------------- K-split 64x128 GEMM (wo): 2 K-slices -> partials ----------------
__global__ __launch_bounds__(256) void gemm_ks(
    const u16* __restrict__ A, const u16* __restrict__ B,
    u16* __restrict__ C, int M, int N, int K)
{
  constexpr int BM = 64, MT = 2;
  __shared__ __align__(16) u16 As[BM * 64];
  __shared__ __align__(16) u16 Bs[128 * 64];
  const int tid = threadIdx.x;
  const int lane = tid & 63, wave = tid >> 6;
  const int lr = lane & 15, lg = lane >> 4;
  const int wm = wave >> 1, wn = wave & 1;

  const int nwg = gridDim.x * gridDim.y;
  const int id = blockIdx.y * gridDim.x + blockIdx.x;
  const int nid = (id & 7) * (nwg >> 3) + (id >> 3);
  const int bx = nid % gridDim.x, byk = nid / gridDim.x;
  const int kslice = byk & 1, by = byk >> 1;
  const int Kh = K >> 1;
  const int kofs = kslice * Kh;
  u16* Cs = C + (size_t)kslice * M * N;

  const int srow = tid >> 3;
  const int scsw = ((tid & 7) * 8) ^ ((srow & 7) << 3);
  const size_t abase = (size_t)(by * BM + srow) * K + kofs + scsw;
  const size_t bbase = (size_t)(bx * 128 + srow) * K + kofs + scsw;

  int aoff[MT][2], boff[4][2];
  #pragma unroll
  for (int mt = 0; mt < MT; mt++) {
    int row = wm * (BM / 2) + mt * 16 + lr;
    #pragma unroll
    for (int kk = 0; kk < 2; kk++)
      aoff[mt][kk] = row * 64 + ((kk * 32 + lg * 8) ^ ((row & 7) << 3));
  }
  #pragma unroll
  for (int nt = 0; nt < 4; nt++) {
    int row = wn * 64 + nt * 16 + lr;
    #pragma unroll
    for (int kk = 0; kk < 2; kk++)
      boff[nt][kk] = row * 64 + ((kk * 32 + lg * 8) ^ ((row & 7) << 3));
  }

  f32x4 acc[MT][4];
  #pragma unroll
  for (int i = 0; i < MT; i++)
    #pragma unroll
    for (int j = 0; j < 4; j++) acc[i][j] = (f32x4){0.f, 0.f, 0.f, 0.f};

  for (int k0 = 0; k0 < Kh; k0 += 64) {
    __syncthreads();
    #pragma unroll
    for (int h = 0; h < MT; h++)
      gload16(A + abase + (size_t)(h * 32) * K + k0, &As[h * 2048 + tid * 8]);
    #pragma unroll
    for (int h = 0; h < 4; h++)
      gload16(B + bbase + (size_t)(h * 32) * K + k0, &Bs[h * 2048 + tid * 8]);
    __syncthreads();
    #pragma unroll
    for (int kk = 0; kk < 2; kk++) {
      bf16x8 af[MT], bfr[4];
      #pragma unroll
      for (int mt = 0; mt < MT; mt++) af[mt] = *(const bf16x8*)&As[aoff[mt][kk]];
      #pragma unroll
      for (int nt = 0; nt < 4; nt++) bfr[nt] = *(const bf16x8*)&Bs[boff[nt][kk]];
      #pragma unroll
      for (int mt = 0; mt < MT; mt++)
        #pragma unroll
        for (int nt = 0; nt < 4; nt++)
          acc[mt][nt] = __builtin_amdgcn_mfma_f32_16x16x32_bf16(af[mt], bfr[nt], acc[mt][nt], 0, 0, 0);
    }
  }

  #pragma unroll
  for (int mt = 0; mt < MT; mt++)
    #pragma unroll
    for (int nt = 0; nt < 4; nt++) {
      const int row = by * BM + wm * (BM / 2) + mt * 16 + lg * 4;
      const int col = bx * 128 + wn * 64 + nt * 16 + lr;
      #pragma unroll
      for (int r = 0; r < 4; r++)
        Cs[(size_t)(row + r) * N + col] = f2b(acc[mt][nt][r]);
    }
}

// ---------------- 256^2 8-phase GEMM (r12 proven) ----------------
#define MFMA16(BASE, BF)                                                       \
  __builtin_amdgcn_s_setprio(1);                                               \
  _Pragma("unroll")                                                            \
  for (int mt = 0; mt < 4; mt++)                                               \
    _Pragma("unroll")                                                          \
    for (int nt = 0; nt < 4; nt++)                                             \
      acc[(BASE) + mt][nt] = __builtin_amdgcn_mfma_f32_16x16x32_bf16(          \
          af[mt], BF[nt], acc[(BASE) + mt][nt], 0, 0, 0);                      \
  __builtin_amdgcn_s_setprio(0);

#define SA2(bb, eta, kb)                                                             \
  gload16(Ab + ((size_t)(eta) * 128) * K + (kb), &As[bb][eta][tid * 8]);             \
  gload16(Ab + ((size_t)(eta) * 128 + 64) * K + (kb), &As[bb][eta][4096 + tid * 8]);
#define SB2(bb, eta, kb)                                                             \
  gload16(Bb + ((size_t)(eta) * 128) * K + (kb), &Bs[bb][eta][tid * 8]);             \
  gload16(Bb + ((size_t)(eta) * 128 + 64) * K + (kb), &Bs[bb][eta][4096 + tid * 8]);

#define SBAR asm volatile("s_barrier" ::: "memory")

template<int EPI, int KSPLIT>
__global__ __launch_bounds__(512) void gemm256(
    const u16* __restrict__ A, const u16* __restrict__ B,
    u16* __restrict__ C, const float* __restrict__ bias,
    int M, int N, int K)
{
  __shared__ __align__(16) u16 As[2][2][8192];
  __shared__ __align__(16) u16 Bs[2][2][8192];
  const int tid = threadIdx.x;
  const int lane = tid & 63, wave = tid >> 6;
  const int lr = lane & 15, lg = lane >> 4;
  const int wm = wave >> 2, wn = wave & 3;

  const int nwg = gridDim.x * gridDim.y;
  const int id = blockIdx.y * gridDim.x + blockIdx.x;
  const int nid = (id & 7) * (nwg >> 3) + (id >> 3);
  const int bx = nid % gridDim.x;
  const int byk = nid / gridDim.x;
  const int kslice = (KSPLIT > 1) ? (byk % KSPLIT) : 0;
  const int by = (KSPLIT > 1) ? (byk / KSPLIT) : byk;
  const int Kloc = K / KSPLIT;
  const int kofs = kslice * Kloc;
  u16* Cd = C + (size_t)kslice * M * N;

  const int srow = tid >> 3;
  const int scsw = ((tid & 7) * 8) ^ ((srow & 7) << 3);
  const u16* Ab = A + (size_t)(by * 256 + srow) * K + kofs + scsw;
  const u16* Bb = B + (size_t)(bx * 256 + srow) * K + kofs + scsw;

  int aoff[2][2][4], boff[2][4];
  #pragma unroll
  for (int mh = 0; mh < 2; mh++)
    #pragma unroll
    for (int kk = 0; kk < 2; kk++)
      #pragma unroll
      for (int mt = 0; mt < 4; mt++) {
        int row = mh * 64 + mt * 16 + lr;
        aoff[mh][kk][mt] = row * 64 + ((kk * 32 + lg * 8) ^ ((lr & 7) << 3));
      }
  #pragma unroll
  for (int kk = 0; kk < 2; kk++)
    #pragma unroll
    for (int nt = 0; nt < 4; nt++) {
      int row = (wn & 1) * 64 + nt * 16 + lr;
      boff[kk][nt] = row * 64 + ((kk * 32 + lg * 8) ^ ((lr & 7) << 3));
    }

  f32x4 acc[8][4];
  #pragma unroll
  for (int i = 0; i < 8; i++)
    #pragma unroll
    for (int j = 0; j < 4; j++) acc[i][j] = (f32x4){0.f, 0.f, 0.f, 0.f};

  const int NT = Kloc >> 6;

  SB2(0, 0, 0) SB2(0, 1, 0) SA2(0, 0, 0) SA2(0, 1, 0)

  for (int t = 0; t < NT; ++t) {
    const int c = t & 1, n = c ^ 1;
    const size_t kb = (size_t)(t + 1) * 64;
    const bool st = (t + 1 < NT);
    const u16* Ac = As[c][wm];
    const u16* Bc = Bs[c][wn >> 1];
    bf16x8 b0[4], b1[4], af[4];

    asm volatile("s_waitcnt vmcnt(0)" ::: "memory");
    SBAR;
    #pragma unroll
    for (int nt = 0; nt < 4; nt++) b0[nt] = *(const bf16x8*)&Bc[boff[0][nt]];
    #pragma unroll
    for (int mt = 0; mt < 4; mt++) af[mt] = *(const bf16x8*)&Ac[aoff[0][0][mt]];
    if (st) { SB2(n, 0, kb) }
    MFMA16(0, b0)
    SBAR;
    #pragma unroll
    for (int nt = 0; nt < 4; nt++) b1[nt] = *(const bf16x8*)&Bc[boff[1][nt]];
    #pragma unroll
    for (int mt = 0; mt < 4; mt++) af[mt] = *(const bf16x8*)&Ac[aoff[0][1][mt]];
    if (st) { SA2(n, 0, kb) }
    SBAR;
    MFMA16(0, b1)
    SBAR;
    #pragma unroll
    for (int mt = 0; mt < 4; mt++) af[mt] = *(const bf16x8*)&Ac[aoff[1][0][mt]];
    if (st) { SB2(n, 1, kb) }
    SBAR;
    MFMA16(4, b0)
    SBAR;
    #pragma unroll
    for (int mt = 0; mt < 4; mt++) af[mt] = *(const bf16x8*)&Ac[aoff[1][1][mt]];
    if (st) { SA2(n, 1, kb) }
    SBAR;
    MFMA16(4, b1)
    SBAR;
  }

  #pragma unroll
  for (int m8 = 0; m8 < 8; m8++)
    #pragma unroll
    for (int nt = 0; nt < 4; nt++) {
      const int row = by * 256 + wm * 128 + m8 * 16 + lg * 4;
      const int col = bx * 256 + wn * 64 + nt * 16 + lr;
      const float bv = (EPI >= 1) ? bias[col] : 0.f;
      #pragma unroll
      for (int r = 0; r < 4; r++) {
        float x = acc[m8][nt][r] + bv;
        if (EPI == 2) x = 0.5f * x * (1.f + erff(x * 0.70710678118654752f));
        Cd[(size_t)(row + r) * N + col] = f2b(x);
      }
    }
}

// ---------------- fused RoPE + V-transpose ----------------
__global__ __launch_bounds__(256) void rope_vtrans_kernel(
    const u16* __restrict__ qkv, const float2* __restrict__ tab,
    u16* __restrict__ qr, u16* __restrict__ kr, u16* __restrict__ vT)
{
  __shared__ u16 t[64][65];
  const int bid = blockIdx.x;
  const int bh = bid >> 5, sc = bid & 31;
  const int h = bh & 15, b = bh >> 4;
  const int tid = threadIdx.x;
  const int lane = tid & 63;
  const int j = lane & 31;

  #pragma unroll
  for (int i = 0; i < 16; i++) {
    int idx = i * 256 + tid;
    int sl = idx >> 6, d = idx & 63;
    t[sl][d] = qkv[(size_t)(b * 2048 + sc * 64 + sl) * 3072 + 2048 + h * 64 + d];
  }

  #pragma unroll
  for (int i = 0; i < 16; i++) {
    int s = sc * 64 + i * 4 + (tid >> 6);
    float2 tt = tab[s * 32 + j];
    const float cs = tt.x, sn = tt.y;
    const size_t base = (size_t)(b * 2048 + s) * 3072 + h * 64;
    unsigned int qv = *(const unsigned int*)(qkv + base + 2 * j);
    unsigned int kv = *(const unsigned int*)(qkv + base + 1024 + 2 * j);
    float q1 = b2f((u16)qv), q2 = b2f((u16)(qv >> 16));
    float k1 = b2f((u16)kv), k2 = b2f((u16)(kv >> 16));
    float qo = (lane < 32) ? (q1 * cs - q2 * sn) : (q1 * sn + q2 * cs);
    float ko = (lane < 32) ? (k1 * cs - k2 * sn) : (k1 * sn + k2 * cs);
    qr[(size_t)(bh * 2048 + s) * 64 + lane] = f2b(qo * 0.18033688011112042f);  // 0.125*log2(e)
    kr[(size_t)(bh * 2048 + s) * 64 + lane] = f2b(ko);
  }

  __syncthreads();
  #pragma unroll
  for (int i = 0; i < 16; i++) {
    int idx = i * 256 + tid;
    int d = idx >> 6, sl = idx & 63;
    vT[((size_t)bh * 64 + d) * 2048 + sc * 64 + sl] = t[sl][d];
  }
}

// ---------------- Flash attention: 512thr/8wave, KV-split x2 -> (O/l, lse) partials ----------------
__global__ __launch_bounds__(512) void attn_kernel(
    const u16* __restrict__ qr, const u16* __restrict__ kr,
    const u16* __restrict__ vT, const float* __restrict__ rel_tab,
    u16* __restrict__ Op, float* __restrict__ lse)
{
  __shared__ __align__(16) u16 Ks[2][64 * 64];
  __shared__ __align__(16) u16 Vs[2][64 * 64];
  __shared__ float bias_s[64];

  const int tid = threadIdx.x;
  const int lane = tid & 63, wave = tid >> 6;  // 8 waves
  const int lr = lane & 15, lg = lane >> 4;

  const int id = blockIdx.x;                   // 1024 blocks
  const int nid = (id & 7) * 128 + (id >> 3);
  const int bh = nid >> 5;
  const int qc = (nid >> 1) & 15;
  const int kvs = nid & 1;                     // kv half
  const int h = bh & 15;
  const int q0 = qc * 128 + wave * 16;

  if (tid < 63) bias_s[tid] = rel_tab[tid * 16 + h] * 1.4426950408889634f;

  const u16* qb = qr + (size_t)bh * 2048 * 64;
  const u16* kb = kr + (size_t)bh * 2048 * 64;
  const u16* vb = vT + (size_t)bh * 64 * 2048;

  bf16x8 qf[2];
  qf[0] = *(const bf16x8*)(qb + (size_t)(q0 + lr) * 64 + lg * 8);
  qf[1] = *(const bf16x8*)(qb + (size_t)(q0 + lr) * 64 + 32 + lg * 8);

  const int srow = tid >> 3;
  const int scsw = ((tid & 7) * 8) ^ ((srow & 7) << 3);

  int koff[4][2];
  #pragma unroll
  for (int nt = 0; nt < 4; nt++)
    #pragma unroll
    for (int ks = 0; ks < 2; ks++)
      koff[nt][ks] = (nt * 16 + lr) * 64 + ((ks * 32 + lg * 8) ^ ((lr & 7) << 3));

  const int kbase = kvs * 1024;
  gload16(kb + (size_t)(kbase + srow) * 64 + scsw, &Ks[0][tid * 8]);
  gload16(vb + (size_t)srow * 2048 + kbase + scsw, &Vs[0][tid * 8]);

  float mrow = -1e30f;
  f32x4 lvec = (f32x4){0.f, 0.f, 0.f, 0.f};
  f32x4 oacc[4];
  #pragma unroll
  for (int nt = 0; nt < 4; nt++) oacc[nt] = (f32x4){0.f, 0.f, 0.f, 0.f};

  int cur = 0;
  for (int kc = 0; kc < 16; kc++) {
    const int k0 = kbase + kc * 64;
    __syncthreads();
    if (kc < 15) {
      const int kn = k0 + 64;
      gload16(kb + (size_t)(kn + srow) * 64 + scsw, &Ks[cur ^ 1][tid * 8]);
      gload16(vb + (size_t)srow * 2048 + kn + scsw, &Vs[cur ^ 1][tid * 8]);
    }
    const u16* Kc = Ks[cur];
    const u16* Vc = Vs[cur];

    f32x4 sacc[4];
    #pragma unroll
    for (int nt = 0; nt < 4; nt++) sacc[nt] = (f32x4){0.f, 0.f, 0.f, 0.f};
    __builtin_amdgcn_s_setprio(1);
    #pragma unroll
    for (int ks = 0; ks < 2; ks++)
      #pragma unroll
      for (int nt = 0; nt < 4; nt++) {
        bf16x8 kf = *(const bf16x8*)&Kc[koff[nt][ks]];
        sacc[nt] = __builtin_amdgcn_mfma_f32_16x16x32_bf16(kf, qf[ks], sacc[nt], 0, 0, 0);
      }
    __builtin_amdgcn_s_setprio(0);

    f32x4 pvv[4];
    const int dmin = q0 - k0 - 63, dmax = q0 + 15 - k0;
    if (dmin >= 31 || dmax <= -31) {
      const float c = bias_s[dmin >= 31 ? 62 : 0];
      f32x4 m4;
      #pragma unroll
      for (int i = 0; i < 4; i++)
        m4[i] = fmaxf(fmaxf(sacc[0][i], sacc[1][i]), fmaxf(sacc[2][i], sacc[3][i]));
      float rm = fmaxf(fmaxf(m4[0], m4[1]), fmaxf(m4[2], m4[3])) + c;
      rm = fmaxf(rm, __shfl_xor(rm, 16));
      rm = fmaxf(rm, __shfl_xor(rm, 32));
      if (!__all(rm <= mrow + 11.5f)) {
        float mnew = fmaxf(mrow, rm);
        float sc = exp2f(mrow - mnew);
        lvec *= sc;
        #pragma unroll
        for (int nt = 0; nt < 4; nt++) oacc[nt] *= sc;
        mrow = mnew;
      }
      const float off = c - mrow;
      #pragma unroll
      for (int nt = 0; nt < 4; nt++) pvv[nt] = sacc[nt] + off;
    } else {
      #pragma unroll
      for (int nt = 0; nt < 4; nt++)
        #pragma unroll
        for (int r = 0; r < 4; r++) {
          int d = (q0 + lr) - (k0 + nt * 16 + lg * 4 + r);
          d = d < -31 ? -31 : (d > 31 ? 31 : d);
          pvv[nt][r] = sacc[nt][r] + bias_s[d + 31];
        }
      f32x4 m4;
      #pragma unroll
      for (int i = 0; i < 4; i++)
        m4[i] = fmaxf(fmaxf(pvv[0][i], pvv[1][i]), fmaxf(pvv[2][i], pvv[3][i]));
      float rm = fmaxf(fmaxf(m4[0], m4[1]), fmaxf(m4[2], m4[3]));
      rm = fmaxf(rm, __shfl_xor(rm, 16));
      rm = fmaxf(rm, __shfl_xor(rm, 32));
      if (!__all(rm <= mrow + 11.5f)) {
        float mnew = fmaxf(mrow, rm);
        float sc = exp2f(mrow - mnew);
        lvec *= sc;
        #pragma unroll
        for (int nt = 0; nt < 4; nt++) oacc[nt] *= sc;
        mrow = mnew;
      }
      #pragma unroll
      for (int nt = 0; nt < 4; nt++) pvv[nt] = pvv[nt] - mrow;
    }

    unsigned int pk[4][2];
    #pragma unroll
    for (int nt = 0; nt < 4; nt++) {
      f32x4 p;
      #pragma unroll
      for (int i = 0; i < 4; i++) p[i] = exp2f(pvv[nt][i]);
      lvec += p;
      unsigned int pr0, pr1;
      asm("v_cvt_pk_bf16_f32 %0, %1, %2" : "=v"(pr0) : "v"(p[0]), "v"(p[1]));
      asm("v_cvt_pk_bf16_f32 %0, %1, %2" : "=v"(pr1) : "v"(p[2]), "v"(p[3]));
      pk[nt][0] = pr0;
      pk[nt][1] = pr1;
    }

    __builtin_amdgcn_s_setprio(1);
    #pragma unroll
    for (int ks = 0; ks < 2; ks++) {
      unsigned int r0 = pk[2 * ks][0], r1 = pk[2 * ks][1];
      unsigned int r2 = pk[2 * ks + 1][0], r3 = pk[2 * ks + 1][1];
      asm("v_permlane32_swap_b32 %0, %1" : "+v"(r0), "+v"(r2));
      asm("v_permlane32_swap_b32 %0, %1" : "+v"(r1), "+v"(r3));
      asm("v_permlane16_swap_b32 %0, %1" : "+v"(r0), "+v"(r2));
      asm("v_permlane16_swap_b32 %0, %1" : "+v"(r1), "+v"(r3));
      int4 bw = make_int4((int)r0, (int)r1, (int)r2, (int)r3);
      bf16x8 pf = *(bf16x8*)&bw;
      #pragma unroll
      for (int nt = 0; nt < 4; nt++) {
        bf16x8 vf = *(const bf16x8*)&Vc[koff[nt][ks]];
        oacc[nt] = __builtin_amdgcn_mfma_f32_16x16x32_bf16(vf, pf, oacc[nt], 0, 0, 0);
      }
    }
    __builtin_amdgcn_s_setprio(0);
    cur ^= 1;
  }

  float lpart = (lvec[0] + lvec[1]) + (lvec[2] + lvec[3]);
  lpart += __shfl_xor(lpart, 16);
  lpart += __shfl_xor(lpart, 32);
  const float inv = 1.0f / lpart;
  // partials: O/l (bf16) + lse = mrow + log2(l) (f32), linear [kvs][bh*2048+q][64]
  const size_t prow = (size_t)kvs * 2048 * 2048 + (size_t)bh * 2048 * 64;
  const size_t obase = prow + (size_t)(q0 + lr) * 64;
  #pragma unroll
  for (int nt = 0; nt < 4; nt++) {
    uint2 st;
    st.x = (unsigned)f2b(oacc[nt][0] * inv) | ((unsigned)f2b(oacc[nt][1] * inv) << 16);
    st.y = (unsigned)f2b(oacc[nt][2] * inv) | ((unsigned)f2b(oacc[nt][3] * inv) << 16);
    *(uint2*)(Op + obase + nt * 16 + lg * 4) = st;
  }
  if (lg == 0)
    lse[(size_t)kvs * 65536 + bh * 2048 + q0 + lr] = mrow + log2f(lpart);
}

// ---------------- attention combine: ob = softmax-weighted blend of 2 partials ----------------
__global__ __launch_bounds__(256) void attn_combine_kernel(
    const u16* __restrict__ Op, const float* __restrict__ lse,
    u16* __restrict__ o)
{
  const int tid = threadIdx.x;
  const int ridx = blockIdx.x * 16 + (tid >> 4);  // bh*2048 + q
  const int dq = (tid & 15) * 4;
  const int bh = ridx >> 11, q = ridx & 2047;
  const int h = bh & 15, b = bh >> 4;

  float l1 = lse[ridx], l2 = lse[65536 + ridx];
  float m = fmaxf(l1, l2);
  float w1 = exp2f(l1 - m), w2 = exp2f(l2 - m);
  float invw = 1.0f / (w1 + w2);
  w1 *= invw; w2 *= invw;

  const size_t pofs = (size_t)ridx * 64 + dq;
  uint2 o1 = *(const uint2*)(Op + pofs);
  uint2 o2 = *(const uint2*)(Op + (size_t)2048 * 2048 + pofs);
  uint2 st;
  st.x = (unsigned)f2b(w1 * b2f((u16)o1.x) + w2 * b2f((u16)o2.x)) |
         ((unsigned)f2b(w1 * b2f((u16)(o1.x >> 16)) + w2 * b2f((u16)(o2.x >> 16))) << 16);
  st.y = (unsigned)f2b(w1 * b2f((u16)o1.y) + w2 * b2f((u16)o2.y)) |
         ((unsigned)f2b(w1 * b2f((u16)(o1.y >> 16)) + w2 * b2f((u16)(o2.y >> 16))) << 16);
  *(uint2*)(o + (size_t)(b * 2048 + q) * 1024 + h * 64 + dq) = st;
}

// ---------------- LayerNorm 1: h = LN(x + ao0 + ao1 + wo_b) ----------------
__global__ __launch_bounds__(256) void ln1_kernel(
    const float* __restrict__ x, const u16* __restrict__ ao0,
    const u16* __restrict__ ao1, const float* __restrict__ wob,
    const float* __restrict__ g, const float* __restrict__ bta,
    u16* __restrict__ hb)
{
  const int row = blockIdx.x, tid = threadIdx.x;
  const int wave = tid >> 6, lane = tid & 63;
  const int c = tid * 4;
  float4 xv = *(const float4*)(x + (size_t)row * 1024 + c);
  uint2 a0 = *(const uint2*)(ao0 + (size_t)row * 1024 + c);
  uint2 a1 = *(const uint2*)(ao1 + (size_t)row * 1024 + c);
  float4 wb = *(const float4*)(wob + c);
  float v0 = xv.x + b2f((u16)a0.x) + b2f((u16)a1.x) + wb.x;
  float v1 = xv.y + b2f((u16)(a0.x >> 16)) + b2f((u16)(a1.x >> 16)) + wb.y;
  float v2 = xv.z + b2f((u16)a0.y) + b2f((u16)a1.y) + wb.z;
  float v3 = xv.w + b2f((u16)(a0.y >> 16)) + b2f((u16)(a1.y >> 16)) + wb.w;
  float s = (v0 + v1) + (v2 + v3);
  float s2 = (v0 * v0 + v1 * v1) + (v2 * v2 + v3 * v3);
  #pragma unroll
  for (int off = 32; off >= 1; off >>= 1) { s += __shfl_down(s, off); s2 += __shfl_down(s2, off); }
  __shared__ float rs[4], rs2[4];
  if (lane == 0) { rs[wave] = s; rs2[wave] = s2; }
  __syncthreads();
  s = rs[0] + rs[1] + rs[2] + rs[3];
  s2 = rs2[0] + rs2[1] + rs2[2] + rs2[3];
  float mean = s * (1.f / 1024.f);
  float var = s2 * (1.f / 1024.f) - mean * mean;
  float inv = rsqrtf(var + 1e-5f);
  float4 gv = *(const float4*)(g + c);
  float4 bv = *(const float4*)(bta + c);
  uint2 ov;
  ov.x = (unsigned)f2b((v0 - mean) * inv * gv.x + bv.x) |
         ((unsigned)f2b((v1 - mean) * inv * gv.y + bv.y) << 16);
  ov.y = (unsigned)f2b((v2 - mean) * inv * gv.z + bv.z) |
         ((unsigned)f2b((v3 - mean) * inv * gv.w + bv.w) << 16);
  *(uint2*)(hb + (size_t)row * 1024 + c) = ov;
}

// ---------------- LayerNorm 2: out = LN(hb + fb0..3 + b2) ----------------
__global__ __launch_bounds__(256) void ln2_kernel(
    const u16* __restrict__ hb, const u16* __restrict__ fb, size_t fstride,
    const float* __restrict__ b2,
    const float* __restrict__ g, const float* __restrict__ bta,
    float* __restrict__ out)
{
  const int row = blockIdx.x, tid = threadIdx.x;
  const int wave = tid >> 6, lane = tid & 63;
  const int c = tid * 4;
  uint2 hv = *(const uint2*)(hb + (size_t)row * 1024 + c);
  float4 b2v = *(const float4*)(b2 + c);
  float v0 = b2f((u16)hv.x) + b2v.x;
  float v1 = b2f((u16)(hv.x >> 16)) + b2v.y;
  float v2 = b2f((u16)hv.y) + b2v.z;
  float v3 = b2f((u16)(hv.y >> 16)) + b2v.w;
  #pragma unroll
  for (int k = 0; k < 4; k++) {
    uint2 fv = *(const uint2*)(fb + k * fstride + (size_t)row * 1024 + c);
    v0 += b2f((u16)fv.x);
    v1 += b2f((u16)(fv.x >> 16));
    v2 += b2f((u16)fv.y);
    v3 += b2f((u16)(fv.y >> 16));
  }
  float s = (v0 + v1) + (v2 + v3);
  float s2 = (v0 * v0 + v1 * v1) + (v2 * v2 + v3 * v3);
  #pragma unroll
  for (int off = 32; off >= 1; off >>= 1) { s += __shfl_down(s, off); s2 += __shfl_down(s2, off); }
  __shared__ float rs[4], rs2[4];
  if (lane == 0) { rs[wave] = s; rs2[wave] = s2; }
  __syncthreads();
  s = rs[0] + rs[1] + rs[2] + rs[3];
  s2 = rs2[0] + rs2[1] + rs2[2] + rs2[3];
  float mean = s * (1.f / 1024.f);
  float var = s2 * (1.f / 1024.f) - mean * mean;
  float inv = rsqrtf(var + 1e-5f);
  float4 gv = *(const float4*)(g + c);
  float4 bv = *(const float4*)(bta + c);
  float4 ov;
  ov.x = (v0 - mean) * inv * gv.x + bv.x;
  ov.y = (v1 - mean) * inv * gv.y + bv.y;
  ov.z = (v2 - mean) * inv * gv.z + bv.z;
  ov.w = (v3 - mean) * inv * gv.w + bv.w;
  *(float4*)(out + (size_t)row * 1024 + c) = ov;
}

// ---------------- host launcher ----------------
extern "C" void kernel_launch(void* const* d_in, const int* in_sizes, int n_in,
                              void* d_out, int out_size, void* d_ws, size_t ws_size,
                              hipStream_t stream)
{
  const float* x    = (const float*)d_in[0];
  const float* wq   = (const float*)d_in[1];
  const float* wk   = (const float*)d_in[2];
  const float* wv   = (const float*)d_in[3];
  const float* wo   = (const float*)d_in[4];
  const float* wo_b = (const float*)d_in[5];
  const float* rel  = (const float*)d_in[6];
  const float* ln1g = (const float*)d_in[7];
  const float* ln1b = (const float*)d_in[8];
  const float* ln2g = (const float*)d_in[9];
  const float* ln2b = (const float*)d_in[10];
  const float* w1   = (const float*)d_in[11];
  const float* b1   = (const float*)d_in[12];
  const float* w2   = (const float*)d_in[13];
  const float* b2   = (const float*)d_in[14];
  float* out = (float*)d_out;
  char* w = (char*)d_ws;

  if (ws_size < (size_t)106 * MB) return;

  // layout (MB): [xb 0-8][wqkvb 8-14][wob 14-16][w1b 16-24][qkv 32-56: ob@32/ao@40]
  // [qrb 56][krb 64][vTb 72][Opart 80-96 (2x8, attn-time only)][w2b 96-104][tab 104]
  // lse 2x256KB at 24-24.5 (free gap); hb@32 after wo; gb 56-88; fb 0-32 (FFN2)
  u16* xb    = (u16*)(w + 0 * MB);
  u16* wqkvb = (u16*)(w + 8 * MB);
  u16* wob   = (u16*)(w + 14 * MB);
  u16* w1b   = (u16*)(w + 16 * MB);
  u16* w2b   = (u16*)(w + 96 * MB);
  u16* qkv   = (u16*)(w + 32 * MB);
  u16* ob    = (u16*)(w + 32 * MB);
  u16* ao01  = (u16*)(w + 40 * MB);
  u16* hb    = (u16*)(w + 32 * MB);
  u16* qrb   = (u16*)(w + 56 * MB);
  u16* krb   = (u16*)(w + 64 * MB);
  u16* vTb   = (u16*)(w + 72 * MB);
  u16* gb    = (u16*)(w + 56 * MB);
  u16* fb    = (u16*)(w + 0 * MB);
  u16* Opart = (u16*)(w + 80 * MB);        // 2 x 8 MB
  float* lseb = (float*)(w + 24 * MB);     // 2 x 256 KB
  float2* tab = (float2*)(w + 104 * MB);

  const int M = 4096, D = 1024, F = 4096;

  rope_tab_kernel<<<dim3(256), 256, 0, stream>>>(tab);
  f2b_all<<<dim3(16384), 256, 0, stream>>>(x, wq, wk, wv, wo, w1, w2,
                                           xb, wqkvb, wob, w1b, w2b);

  gemm256<0, 1><<<dim3(3 * D / 256, M / 256), 512, 0, stream>>>(xb, wqkvb, qkv, nullptr, M, 3 * D, D);

  rope_vtrans_kernel<<<dim3(1024), 256, 0, stream>>>(qkv, tab, qrb, krb, vTb);

  // attention: KV-split x2 -> partials, then combine
  attn_kernel<<<dim3(1024), 512, 0, stream>>>(qrb, krb, vTb, rel, Opart, lseb);
  attn_combine_kernel<<<dim3(4096), 256, 0, stream>>>(Opart, lseb, ob);

  // wo projection: K-split x2 -> ao0, ao1 (wo_b folded into ln1)
  gemm_ks<<<dim3(D / 128, (M / 64) * 2), 256, 0, stream>>>(ob, wob, ao01, M, D, D);

  ln1_kernel<<<dim3(M), 256, 0, stream>>>(x, ao01, ao01 + (size_t)M * D, wo_b,
                                          ln1g, ln1b, hb);

  gemm256<2, 1><<<dim3(F / 256, M / 256), 512, 0, stream>>>(hb, w1b, gb, b1, M, F, D);

  // FFN2: 256^2 8-phase, K-split x4 -> fb[0..3] (b2 folded into ln2)
  gemm256<0, 4><<<dim3(D / 256, (M / 256) * 4), 512, 0, stream>>>(gb, w2b, fb, nullptr, M, D, F);

  ln2_kernel<<<dim3(M), 256, 0, stream>>>(hb, fb, (size_t)M * D, b2,
                                          ln2g, ln2b, out);
}

// Round 16
// 255.134 us; speedup vs baseline: 1.0323x; 1.0323x over previous
//
#include <hip/hip_runtime.h>
#include <stdint.h>

#define MB (1ull << 20)
typedef unsigned short u16;
typedef __attribute__((ext_vector_type(8))) short bf16x8;
typedef __attribute__((ext_vector_type(4))) float f32x4;

__device__ __forceinline__ float b2f(u16 u) {
  union { unsigned int i; float f; } c; c.i = ((unsigned int)u) << 16; return c.f;
}
__device__ __forceinline__ u16 f2b(float f) {
  union { float f; unsigned int i; } c; c.f = f;
  unsigned int r = c.i + 0x7fffu + ((c.i >> 16) & 1u);
  return (u16)(r >> 16);
}
__device__ __forceinline__ void gload16(const void* g, void* l) {
  __builtin_amdgcn_global_load_lds(
      (const __attribute__((address_space(1))) void*)g,
      (__attribute__((address_space(3))) void*)l, 16, 0, 0);
}

// ---------------- fused f32 -> bf16 convert + RoPE table ----------------
__global__ __launch_bounds__(256) void f2b_all(
    const float* __restrict__ x, const float* __restrict__ wq, const float* __restrict__ wk,
    const float* __restrict__ wv, const float* __restrict__ wo, const float* __restrict__ w1,
    const float* __restrict__ w2,
    u16* __restrict__ xb, u16* __restrict__ wqkvb, u16* __restrict__ wob,
    u16* __restrict__ w1b, u16* __restrict__ w2b, float2* __restrict__ tab)
{
  int bid = blockIdx.x;
  if (bid >= 16384) {  // RoPE cos/sin table: 256 blocks
    int idx = (bid - 16384) * 256 + threadIdx.x;
    int s = idx >> 5, j = idx & 31;
    float inv = exp2f(-(float)j * (13.287712379549449f / 32.0f));
    float sn, cs;
    sincosf((float)s * inv, &sn, &cs);
    tab[idx] = make_float2(cs, sn);
    return;
  }
  const float* src; u16* dst;
  if (bid < 4096)       { src = x;  dst = xb; }
  else if (bid < 5120)  { src = wq; dst = wqkvb;           bid -= 4096; }
  else if (bid < 6144)  { src = wk; dst = wqkvb + 1048576; bid -= 5120; }
  else if (bid < 7168)  { src = wv; dst = wqkvb + 2097152; bid -= 6144; }
  else if (bid < 8192)  { src = wo; dst = wob;             bid -= 7168; }
  else if (bid < 12288) { src = w1; dst = w1b;             bid -= 8192; }
  else                  { src = w2; dst = w2b;             bid -= 12288; }
  int i = (bid * 256 + threadIdx.x) * 4;
  float4 v = *(const float4*)(src + i);
  uint2 ov;
  ov.x = (unsigned)f2b(v.x) | ((unsigned)f2b(v.y) << 16);
  ov.y = (unsigned)f2b(v.z) | ((unsigned)f2b(v.w) << 16);
  *(uint2*)(dst + i) = ov;
}

// ---------------- K-split 64x128 GEMM (wo): 2 K-slices -> partials ----------------
__global__ __launch_bounds__(256) void gemm_ks(
    const u16* __restrict__ A, const u16* __restrict__ B,
    u16* __restrict__ C, int M, int N, int K)
{
  constexpr int BM = 64, MT = 2;
  __shared__ __align__(16) u16 As[BM * 64];
  __shared__ __align__(16) u16 Bs[128 * 64];
  const int tid = threadIdx.x;
  const int lane = tid & 63, wave = tid >> 6;
  const int lr = lane & 15, lg = lane >> 4;
  const int wm = wave >> 1, wn = wave & 1;

  const int nwg = gridDim.x * gridDim.y;
  const int id = blockIdx.y * gridDim.x + blockIdx.x;
  const int nid = (id & 7) * (nwg >> 3) + (id >> 3);
  const int bx = nid % gridDim.x, byk = nid / gridDim.x;
  const int kslice = byk & 1, by = byk >> 1;
  const int Kh = K >> 1;
  const int kofs = kslice * Kh;
  u16* Cs = C + (size_t)kslice * M * N;

  const int srow = tid >> 3;
  const int scsw = ((tid & 7) * 8) ^ ((srow & 7) << 3);
  const size_t abase = (size_t)(by * BM + srow) * K + kofs + scsw;
  const size_t bbase = (size_t)(bx * 128 + srow) * K + kofs + scsw;

  int aoff[MT][2], boff[4][2];
  #pragma unroll
  for (int mt = 0; mt < MT; mt++) {
    int row = wm * (BM / 2) + mt * 16 + lr;
    #pragma unroll
    for (int kk = 0; kk < 2; kk++)
      aoff[mt][kk] = row * 64 + ((kk * 32 + lg * 8) ^ ((row & 7) << 3));
  }
  #pragma unroll
  for (int nt = 0; nt < 4; nt++) {
    int row = wn * 64 + nt * 16 + lr;
    #pragma unroll
    for (int kk = 0; kk < 2; kk++)
      boff[nt][kk] = row * 64 + ((kk * 32 + lg * 8) ^ ((row & 7) << 3));
  }

  f32x4 acc[MT][4];
  #pragma unroll
  for (int i = 0; i < MT; i++)
    #pragma unroll
    for (int j = 0; j < 4; j++) acc[i][j] = (f32x4){0.f, 0.f, 0.f, 0.f};

  for (int k0 = 0; k0 < Kh; k0 += 64) {
    __syncthreads();
    #pragma unroll
    for (int h = 0; h < MT; h++)
      gload16(A + abase + (size_t)(h * 32) * K + k0, &As[h * 2048 + tid * 8]);
    #pragma unroll
    for (int h = 0; h < 4; h++)
      gload16(B + bbase + (size_t)(h * 32) * K + k0, &Bs[h * 2048 + tid * 8]);
    __syncthreads();
    #pragma unroll
    for (int kk = 0; kk < 2; kk++) {
      bf16x8 af[MT], bfr[4];
      #pragma unroll
      for (int mt = 0; mt < MT; mt++) af[mt] = *(const bf16x8*)&As[aoff[mt][kk]];
      #pragma unroll
      for (int nt = 0; nt < 4; nt++) bfr[nt] = *(const bf16x8*)&Bs[boff[nt][kk]];
      #pragma unroll
      for (int mt = 0; mt < MT; mt++)
        #pragma unroll
        for (int nt = 0; nt < 4; nt++)
          acc[mt][nt] = __builtin_amdgcn_mfma_f32_16x16x32_bf16(af[mt], bfr[nt], acc[mt][nt], 0, 0, 0);
    }
  }

  #pragma unroll
  for (int mt = 0; mt < MT; mt++)
    #pragma unroll
    for (int nt = 0; nt < 4; nt++) {
      const int row = by * BM + wm * (BM / 2) + mt * 16 + lg * 4;
      const int col = bx * 128 + wn * 64 + nt * 16 + lr;
      #pragma unroll
      for (int r = 0; r < 4; r++)
        Cs[(size_t)(row + r) * N + col] = f2b(acc[mt][nt][r]);
    }
}

// ---------------- 256^2 8-phase GEMM (r12 proven) ----------------
#define MFMA16(BASE, BF)                                                       \
  __builtin_amdgcn_s_setprio(1);                                               \
  _Pragma("unroll")                                                            \
  for (int mt = 0; mt < 4; mt++)                                               \
    _Pragma("unroll")                                                          \
    for (int nt = 0; nt < 4; nt++)                                             \
      acc[(BASE) + mt][nt] = __builtin_amdgcn_mfma_f32_16x16x32_bf16(          \
          af[mt], BF[nt], acc[(BASE) + mt][nt], 0, 0, 0);                      \
  __builtin_amdgcn_s_setprio(0);

#define SA2(bb, eta, kb)                                                             \
  gload16(Ab + ((size_t)(eta) * 128) * K + (kb), &As[bb][eta][tid * 8]);             \
  gload16(Ab + ((size_t)(eta) * 128 + 64) * K + (kb), &As[bb][eta][4096 + tid * 8]);
#define SB2(bb, eta, kb)                                                             \
  gload16(Bb + ((size_t)(eta) * 128) * K + (kb), &Bs[bb][eta][tid * 8]);             \
  gload16(Bb + ((size_t)(eta) * 128 + 64) * K + (kb), &Bs[bb][eta][4096 + tid * 8]);

#define SBAR asm volatile("s_barrier" ::: "memory")

template<int EPI, int KSPLIT>
__global__ __launch_bounds__(512) void gemm256(
    const u16* __restrict__ A, const u16* __restrict__ B,
    u16* __restrict__ C, const float* __restrict__ bias,
    int M, int N, int K)
{
  __shared__ __align__(16) u16 As[2][2][8192];
  __shared__ __align__(16) u16 Bs[2][2][8192];
  const int tid = threadIdx.x;
  const int lane = tid & 63, wave = tid >> 6;
  const int lr = lane & 15, lg = lane >> 4;
  const int wm = wave >> 2, wn = wave & 3;

  const int nwg = gridDim.x * gridDim.y;
  const int id = blockIdx.y * gridDim.x + blockIdx.x;
  const int nid = (id & 7) * (nwg >> 3) + (id >> 3);
  const int bx = nid % gridDim.x;
  const int byk = nid / gridDim.x;
  const int kslice = (KSPLIT > 1) ? (byk % KSPLIT) : 0;
  const int by = (KSPLIT > 1) ? (byk / KSPLIT) : byk;
  const int Kloc = K / KSPLIT;
  const int kofs = kslice * Kloc;
  u16* Cd = C + (size_t)kslice * M * N;

  const int srow = tid >> 3;
  const int scsw = ((tid & 7) * 8) ^ ((srow & 7) << 3);
  const u16* Ab = A + (size_t)(by * 256 + srow) * K + kofs + scsw;
  const u16* Bb = B + (size_t)(bx * 256 + srow) * K + kofs + scsw;

  int aoff[2][2][4], boff[2][4];
  #pragma unroll
  for (int mh = 0; mh < 2; mh++)
    #pragma unroll
    for (int kk = 0; kk < 2; kk++)
      #pragma unroll
      for (int mt = 0; mt < 4; mt++) {
        int row = mh * 64 + mt * 16 + lr;
        aoff[mh][kk][mt] = row * 64 + ((kk * 32 + lg * 8) ^ ((lr & 7) << 3));
      }
  #pragma unroll
  for (int kk = 0; kk < 2; kk++)
    #pragma unroll
    for (int nt = 0; nt < 4; nt++) {
      int row = (wn & 1) * 64 + nt * 16 + lr;
      boff[kk][nt] = row * 64 + ((kk * 32 + lg * 8) ^ ((lr & 7) << 3));
    }

  f32x4 acc[8][4];
  #pragma unroll
  for (int i = 0; i < 8; i++)
    #pragma unroll
    for (int j = 0; j < 4; j++) acc[i][j] = (f32x4){0.f, 0.f, 0.f, 0.f};

  const int NT = Kloc >> 6;

  SB2(0, 0, 0) SB2(0, 1, 0) SA2(0, 0, 0) SA2(0, 1, 0)

  for (int t = 0; t < NT; ++t) {
    const int c = t & 1, n = c ^ 1;
    const size_t kb = (size_t)(t + 1) * 64;
    const bool st = (t + 1 < NT);
    const u16* Ac = As[c][wm];
    const u16* Bc = Bs[c][wn >> 1];
    bf16x8 b0[4], b1[4], af[4];

    asm volatile("s_waitcnt vmcnt(0)" ::: "memory");
    SBAR;
    #pragma unroll
    for (int nt = 0; nt < 4; nt++) b0[nt] = *(const bf16x8*)&Bc[boff[0][nt]];
    #pragma unroll
    for (int mt = 0; mt < 4; mt++) af[mt] = *(const bf16x8*)&Ac[aoff[0][0][mt]];
    if (st) { SB2(n, 0, kb) }
    MFMA16(0, b0)
    SBAR;
    #pragma unroll
    for (int nt = 0; nt < 4; nt++) b1[nt] = *(const bf16x8*)&Bc[boff[1][nt]];
    #pragma unroll
    for (int mt = 0; mt < 4; mt++) af[mt] = *(const bf16x8*)&Ac[aoff[0][1][mt]];
    if (st) { SA2(n, 0, kb) }
    SBAR;
    MFMA16(0, b1)
    SBAR;
    #pragma unroll
    for (int mt = 0; mt < 4; mt++) af[mt] = *(const bf16x8*)&Ac[aoff[1][0][mt]];
    if (st) { SB2(n, 1, kb) }
    SBAR;
    MFMA16(4, b0)
    SBAR;
    #pragma unroll
    for (int mt = 0; mt < 4; mt++) af[mt] = *(const bf16x8*)&Ac[aoff[1][1][mt]];
    if (st) { SA2(n, 1, kb) }
    SBAR;
    MFMA16(4, b1)
    SBAR;
  }

  #pragma unroll
  for (int m8 = 0; m8 < 8; m8++)
    #pragma unroll
    for (int nt = 0; nt < 4; nt++) {
      const int row = by * 256 + wm * 128 + m8 * 16 + lg * 4;
      const int col = bx * 256 + wn * 64 + nt * 16 + lr;
      const float bv = (EPI >= 1) ? bias[col] : 0.f;
      #pragma unroll
      for (int r = 0; r < 4; r++) {
        float x = acc[m8][nt][r] + bv;
        if (EPI == 2) x = 0.5f * x * (1.f + erff(x * 0.70710678118654752f));
        Cd[(size_t)(row + r) * N + col] = f2b(x);
      }
    }
}

// ---------------- fused RoPE + V-transpose ----------------
__global__ __launch_bounds__(256) void rope_vtrans_kernel(
    const u16* __restrict__ qkv, const float2* __restrict__ tab,
    u16* __restrict__ qr, u16* __restrict__ kr, u16* __restrict__ vT)
{
  __shared__ u16 t[64][65];
  const int bid = blockIdx.x;
  const int bh = bid >> 5, sc = bid & 31;
  const int h = bh & 15, b = bh >> 4;
  const int tid = threadIdx.x;
  const int lane = tid & 63;
  const int j = lane & 31;

  #pragma unroll
  for (int i = 0; i < 16; i++) {
    int idx = i * 256 + tid;
    int sl = idx >> 6, d = idx & 63;
    t[sl][d] = qkv[(size_t)(b * 2048 + sc * 64 + sl) * 3072 + 2048 + h * 64 + d];
  }

  #pragma unroll
  for (int i = 0; i < 16; i++) {
    int s = sc * 64 + i * 4 + (tid >> 6);
    float2 tt = tab[s * 32 + j];
    const float cs = tt.x, sn = tt.y;
    const size_t base = (size_t)(b * 2048 + s) * 3072 + h * 64;
    unsigned int qv = *(const unsigned int*)(qkv + base + 2 * j);
    unsigned int kv = *(const unsigned int*)(qkv + base + 1024 + 2 * j);
    float q1 = b2f((u16)qv), q2 = b2f((u16)(qv >> 16));
    float k1 = b2f((u16)kv), k2 = b2f((u16)(kv >> 16));
    float qo = (lane < 32) ? (q1 * cs - q2 * sn) : (q1 * sn + q2 * cs);
    float ko = (lane < 32) ? (k1 * cs - k2 * sn) : (k1 * sn + k2 * cs);
    qr[(size_t)(bh * 2048 + s) * 64 + lane] = f2b(qo * 0.18033688011112042f);  // 0.125*log2(e)
    kr[(size_t)(bh * 2048 + s) * 64 + lane] = f2b(ko);
  }

  __syncthreads();
  #pragma unroll
  for (int i = 0; i < 16; i++) {
    int idx = i * 256 + tid;
    int d = idx >> 6, sl = idx & 63;
    vT[((size_t)bh * 64 + d) * 2048 + sc * 64 + sl] = t[sl][d];
  }
}

// ---------------- Flash attention (r14 final: 512thr/8wave, permlane, K+V LDS) ----------------
__global__ __launch_bounds__(512) void attn_kernel(
    const u16* __restrict__ qr, const u16* __restrict__ kr,
    const u16* __restrict__ vT, const float* __restrict__ rel_tab,
    u16* __restrict__ o)
{
  __shared__ __align__(16) u16 Ks[2][64 * 64];
  __shared__ __align__(16) u16 Vs[2][64 * 64];
  __shared__ float bias_s[64];

  const int tid = threadIdx.x;
  const int lane = tid & 63, wave = tid >> 6;  // 8 waves
  const int lr = lane & 15, lg = lane >> 4;

  const int id = blockIdx.x;                   // 512 blocks
  const int nid = (id & 7) * 64 + (id >> 3);
  const int bh = nid >> 4, qc = nid & 15;      // 128 q-rows per block
  const int h = bh & 15, b = bh >> 4;
  const int q0 = qc * 128 + wave * 16;

  if (tid < 63) bias_s[tid] = rel_tab[tid * 16 + h] * 1.4426950408889634f;

  const u16* qb = qr + (size_t)bh * 2048 * 64;
  const u16* kb = kr + (size_t)bh * 2048 * 64;
  const u16* vb = vT + (size_t)bh * 64 * 2048;

  bf16x8 qf[2];
  qf[0] = *(const bf16x8*)(qb + (size_t)(q0 + lr) * 64 + lg * 8);
  qf[1] = *(const bf16x8*)(qb + (size_t)(q0 + lr) * 64 + 32 + lg * 8);

  const int srow = tid >> 3;
  const int scsw = ((tid & 7) * 8) ^ ((srow & 7) << 3);

  int koff[4][2];
  #pragma unroll
  for (int nt = 0; nt < 4; nt++)
    #pragma unroll
    for (int ks = 0; ks < 2; ks++)
      koff[nt][ks] = (nt * 16 + lr) * 64 + ((ks * 32 + lg * 8) ^ ((lr & 7) << 3));

  gload16(kb + (size_t)srow * 64 + scsw, &Ks[0][tid * 8]);
  gload16(vb + (size_t)srow * 2048 + scsw, &Vs[0][tid * 8]);

  float mrow = -1e30f;
  f32x4 lvec = (f32x4){0.f, 0.f, 0.f, 0.f};
  f32x4 oacc[4];
  #pragma unroll
  for (int nt = 0; nt < 4; nt++) oacc[nt] = (f32x4){0.f, 0.f, 0.f, 0.f};

  int cur = 0;
  for (int kc = 0; kc < 32; kc++) {
    const int k0 = kc * 64;
    __syncthreads();
    if (kc < 31) {
      const int kn = k0 + 64;
      gload16(kb + (size_t)(kn + srow) * 64 + scsw, &Ks[cur ^ 1][tid * 8]);
      gload16(vb + (size_t)srow * 2048 + kn + scsw, &Vs[cur ^ 1][tid * 8]);
    }
    const u16* Kc = Ks[cur];
    const u16* Vc = Vs[cur];

    f32x4 sacc[4];
    #pragma unroll
    for (int nt = 0; nt < 4; nt++) sacc[nt] = (f32x4){0.f, 0.f, 0.f, 0.f};
    __builtin_amdgcn_s_setprio(1);
    #pragma unroll
    for (int ks = 0; ks < 2; ks++)
      #pragma unroll
      for (int nt = 0; nt < 4; nt++) {
        bf16x8 kf = *(const bf16x8*)&Kc[koff[nt][ks]];
        sacc[nt] = __builtin_amdgcn_mfma_f32_16x16x32_bf16(kf, qf[ks], sacc[nt], 0, 0, 0);
      }
    __builtin_amdgcn_s_setprio(0);

    f32x4 pvv[4];
    const int dmin = q0 - k0 - 63, dmax = q0 + 15 - k0;
    if (dmin >= 31 || dmax <= -31) {
      const float c = bias_s[dmin >= 31 ? 62 : 0];
      f32x4 m4;
      #pragma unroll
      for (int i = 0; i < 4; i++)
        m4[i] = fmaxf(fmaxf(sacc[0][i], sacc[1][i]), fmaxf(sacc[2][i], sacc[3][i]));
      float rm = fmaxf(fmaxf(m4[0], m4[1]), fmaxf(m4[2], m4[3])) + c;
      rm = fmaxf(rm, __shfl_xor(rm, 16));
      rm = fmaxf(rm, __shfl_xor(rm, 32));
      if (!__all(rm <= mrow + 11.5f)) {
        float mnew = fmaxf(mrow, rm);
        float sc = exp2f(mrow - mnew);
        lvec *= sc;
        #pragma unroll
        for (int nt = 0; nt < 4; nt++) oacc[nt] *= sc;
        mrow = mnew;
      }
      const float off = c - mrow;
      #pragma unroll
      for (int nt = 0; nt < 4; nt++) pvv[nt] = sacc[nt] + off;
    } else {
      #pragma unroll
      for (int nt = 0; nt < 4; nt++)
        #pragma unroll
        for (int r = 0; r < 4; r++) {
          int d = (q0 + lr) - (k0 + nt * 16 + lg * 4 + r);
          d = d < -31 ? -31 : (d > 31 ? 31 : d);
          pvv[nt][r] = sacc[nt][r] + bias_s[d + 31];
        }
      f32x4 m4;
      #pragma unroll
      for (int i = 0; i < 4; i++)
        m4[i] = fmaxf(fmaxf(pvv[0][i], pvv[1][i]), fmaxf(pvv[2][i], pvv[3][i]));
      float rm = fmaxf(fmaxf(m4[0], m4[1]), fmaxf(m4[2], m4[3]));
      rm = fmaxf(rm, __shfl_xor(rm, 16));
      rm = fmaxf(rm, __shfl_xor(rm, 32));
      if (!__all(rm <= mrow + 11.5f)) {
        float mnew = fmaxf(mrow, rm);
        float sc = exp2f(mrow - mnew);
        lvec *= sc;
        #pragma unroll
        for (int nt = 0; nt < 4; nt++) oacc[nt] *= sc;
        mrow = mnew;
      }
      #pragma unroll
      for (int nt = 0; nt < 4; nt++) pvv[nt] = pvv[nt] - mrow;
    }

    unsigned int pk[4][2];
    #pragma unroll
    for (int nt = 0; nt < 4; nt++) {
      f32x4 p;
      #pragma unroll
      for (int i = 0; i < 4; i++) p[i] = exp2f(pvv[nt][i]);
      lvec += p;
      unsigned int pr0, pr1;
      asm("v_cvt_pk_bf16_f32 %0, %1, %2" : "=v"(pr0) : "v"(p[0]), "v"(p[1]));
      asm("v_cvt_pk_bf16_f32 %0, %1, %2" : "=v"(pr1) : "v"(p[2]), "v"(p[3]));
      pk[nt][0] = pr0;
      pk[nt][1] = pr1;
    }

    __builtin_amdgcn_s_setprio(1);
    #pragma unroll
    for (int ks = 0; ks < 2; ks++) {
      unsigned int r0 = pk[2 * ks][0], r1 = pk[2 * ks][1];
      unsigned int r2 = pk[2 * ks + 1][0], r3 = pk[2 * ks + 1][1];
      asm("v_permlane32_swap_b32 %0, %1" : "+v"(r0), "+v"(r2));
      asm("v_permlane32_swap_b32 %0, %1" : "+v"(r1), "+v"(r3));
      asm("v_permlane16_swap_b32 %0, %1" : "+v"(r0), "+v"(r2));
      asm("v_permlane16_swap_b32 %0, %1" : "+v"(r1), "+v"(r3));
      int4 bw = make_int4((int)r0, (int)r1, (int)r2, (int)r3);
      bf16x8 pf = *(bf16x8*)&bw;
      #pragma unroll
      for (int nt = 0; nt < 4; nt++) {
        bf16x8 vf = *(const bf16x8*)&Vc[koff[nt][ks]];
        oacc[nt] = __builtin_amdgcn_mfma_f32_16x16x32_bf16(vf, pf, oacc[nt], 0, 0, 0);
      }
    }
    __builtin_amdgcn_s_setprio(0);
    cur ^= 1;
  }

  float lpart = (lvec[0] + lvec[1]) + (lvec[2] + lvec[3]);
  lpart += __shfl_xor(lpart, 16);
  lpart += __shfl_xor(lpart, 32);
  const float inv = 1.0f / lpart;
  const size_t obase = (size_t)(b * 2048 + q0 + lr) * 1024 + h * 64;
  #pragma unroll
  for (int nt = 0; nt < 4; nt++) {
    uint2 st;
    st.x = (unsigned)f2b(oacc[nt][0] * inv) | ((unsigned)f2b(oacc[nt][1] * inv) << 16);
    st.y = (unsigned)f2b(oacc[nt][2] * inv) | ((unsigned)f2b(oacc[nt][3] * inv) << 16);
    *(uint2*)(o + obase + nt * 16 + lg * 4) = st;
  }
}

// ---------------- LayerNorm 1: h = LN(x + ao0 + ao1 + wo_b) ----------------
__global__ __launch_bounds__(256) void ln1_kernel(
    const float* __restrict__ x, const u16* __restrict__ ao0,
    const u16* __restrict__ ao1, const float* __restrict__ wob,
    const float* __restrict__ g, const float* __restrict__ bta,
    u16* __restrict__ hb)
{
  const int row = blockIdx.x, tid = threadIdx.x;
  const int wave = tid >> 6, lane = tid & 63;
  const int c = tid * 4;
  float4 xv = *(const float4*)(x + (size_t)row * 1024 + c);
  uint2 a0 = *(const uint2*)(ao0 + (size_t)row * 1024 + c);
  uint2 a1 = *(const uint2*)(ao1 + (size_t)row * 1024 + c);
  float4 wb = *(const float4*)(wob + c);
  float v0 = xv.x + b2f((u16)a0.x) + b2f((u16)a1.x) + wb.x;
  float v1 = xv.y + b2f((u16)(a0.x >> 16)) + b2f((u16)(a1.x >> 16)) + wb.y;
  float v2 = xv.z + b2f((u16)a0.y) + b2f((u16)a1.y) + wb.z;
  float v3 = xv.w + b2f((u16)(a0.y >> 16)) + b2f((u16)(a1.y >> 16)) + wb.w;
  float s = (v0 + v1) + (v2 + v3);
  float s2 = (v0 * v0 + v1 * v1) + (v2 * v2 + v3 * v3);
  #pragma unroll
  for (int off = 32; off >= 1; off >>= 1) { s += __shfl_down(s, off); s2 += __shfl_down(s2, off); }
  __shared__ float rs[4], rs2[4];
  if (lane == 0) { rs[wave] = s; rs2[wave] = s2; }
  __syncthreads();
  s = rs[0] + rs[1] + rs[2] + rs[3];
  s2 = rs2[0] + rs2[1] + rs2[2] + rs2[3];
  float mean = s * (1.f / 1024.f);
  float var = s2 * (1.f / 1024.f) - mean * mean;
  float inv = rsqrtf(var + 1e-5f);
  float4 gv = *(const float4*)(g + c);
  float4 bv = *(const float4*)(bta + c);
  uint2 ov;
  ov.x = (unsigned)f2b((v0 - mean) * inv * gv.x + bv.x) |
         ((unsigned)f2b((v1 - mean) * inv * gv.y + bv.y) << 16);
  ov.y = (unsigned)f2b((v2 - mean) * inv * gv.z + bv.z) |
         ((unsigned)f2b((v3 - mean) * inv * gv.w + bv.w) << 16);
  *(uint2*)(hb + (size_t)row * 1024 + c) = ov;
}

// ---------------- LayerNorm 2: out = LN(hb + fb0..3 + b2) ----------------
__global__ __launch_bounds__(256) void ln2_kernel(
    const u16* __restrict__ hb, const u16* __restrict__ fb, size_t fstride,
    const float* __restrict__ b2,
    const float* __restrict__ g, const float* __restrict__ bta,
    float* __restrict__ out)
{
  const int row = blockIdx.x, tid = threadIdx.x;
  const int wave = tid >> 6, lane = tid & 63;
  const int c = tid * 4;
  uint2 hv = *(const uint2*)(hb + (size_t)row * 1024 + c);
  float4 b2v = *(const float4*)(b2 + c);
  float v0 = b2f((u16)hv.x) + b2v.x;
  float v1 = b2f((u16)(hv.x >> 16)) + b2v.y;
  float v2 = b2f((u16)hv.y) + b2v.z;
  float v3 = b2f((u16)(hv.y >> 16)) + b2v.w;
  #pragma unroll
  for (int k = 0; k < 4; k++) {
    uint2 fv = *(const uint2*)(fb + k * fstride + (size_t)row * 1024 + c);
    v0 += b2f((u16)fv.x);
    v1 += b2f((u16)(fv.x >> 16));
    v2 += b2f((u16)fv.y);
    v3 += b2f((u16)(fv.y >> 16));
  }
  float s = (v0 + v1) + (v2 + v3);
  float s2 = (v0 * v0 + v1 * v1) + (v2 * v2 + v3 * v3);
  #pragma unroll
  for (int off = 32; off >= 1; off >>= 1) { s += __shfl_down(s, off); s2 += __shfl_down(s2, off); }
  __shared__ float rs[4], rs2[4];
  if (lane == 0) { rs[wave] = s; rs2[wave] = s2; }
  __syncthreads();
  s = rs[0] + rs[1] + rs[2] + rs[3];
  s2 = rs2[0] + rs2[1] + rs2[2] + rs2[3];
  float mean = s * (1.f / 1024.f);
  float var = s2 * (1.f / 1024.f) - mean * mean;
  float inv = rsqrtf(var + 1e-5f);
  float4 gv = *(const float4*)(g + c);
  float4 bv = *(const float4*)(bta + c);
  float4 ov;
  ov.x = (v0 - mean) * inv * gv.x + bv.x;
  ov.y = (v1 - mean) * inv * gv.y + bv.y;
  ov.z = (v2 - mean) * inv * gv.z + bv.z;
  ov.w = (v3 - mean) * inv * gv.w + bv.w;
  *(float4*)(out + (size_t)row * 1024 + c) = ov;
}

// ---------------- host launcher ----------------
extern "C" void kernel_launch(void* const* d_in, const int* in_sizes, int n_in,
                              void* d_out, int out_size, void* d_ws, size_t ws_size,
                              hipStream_t stream)
{
  const float* x    = (const float*)d_in[0];
  const float* wq   = (const float*)d_in[1];
  const float* wk   = (const float*)d_in[2];
  const float* wv   = (const float*)d_in[3];
  const float* wo   = (const float*)d_in[4];
  const float* wo_b = (const float*)d_in[5];
  const float* rel  = (const float*)d_in[6];
  const float* ln1g = (const float*)d_in[7];
  const float* ln1b = (const float*)d_in[8];
  const float* ln2g = (const float*)d_in[9];
  const float* ln2b = (const float*)d_in[10];
  const float* w1   = (const float*)d_in[11];
  const float* b1   = (const float*)d_in[12];
  const float* w2   = (const float*)d_in[13];
  const float* b2   = (const float*)d_in[14];
  float* out = (float*)d_out;
  char* w = (char*)d_ws;

  if (ws_size < (size_t)105 * MB) return;

  u16* xb    = (u16*)(w + 0 * MB);
  u16* wqkvb = (u16*)(w + 8 * MB);
  u16* wob   = (u16*)(w + 14 * MB);
  u16* w1b   = (u16*)(w + 16 * MB);
  u16* w2b   = (u16*)(w + 96 * MB);
  u16* qkv   = (u16*)(w + 32 * MB);
  u16* ob    = (u16*)(w + 32 * MB);
  u16* ao01  = (u16*)(w + 40 * MB);
  u16* hb    = (u16*)(w + 32 * MB);
  u16* qrb   = (u16*)(w + 56 * MB);
  u16* krb   = (u16*)(w + 64 * MB);
  u16* vTb   = (u16*)(w + 72 * MB);
  u16* gb    = (u16*)(w + 56 * MB);
  u16* fb    = (u16*)(w + 0 * MB);   // 4 x 8MB partials
  float2* tab = (float2*)(w + 104 * MB);

  const int M = 4096, D = 1024, F = 4096;

  f2b_all<<<dim3(16640), 256, 0, stream>>>(x, wq, wk, wv, wo, w1, w2,
                                           xb, wqkvb, wob, w1b, w2b, tab);

  gemm256<0, 1><<<dim3(3 * D / 256, M / 256), 512, 0, stream>>>(xb, wqkvb, qkv, nullptr, M, 3 * D, D);

  rope_vtrans_kernel<<<dim3(1024), 256, 0, stream>>>(qkv, tab, qrb, krb, vTb);

  attn_kernel<<<dim3(512), 512, 0, stream>>>(qrb, krb, vTb, rel, ob);

  // wo projection: K-split x2 -> ao0, ao1 (wo_b folded into ln1)
  gemm_ks<<<dim3(D / 128, (M / 64) * 2), 256, 0, stream>>>(ob, wob, ao01, M, D, D);

  ln1_kernel<<<dim3(M), 256, 0, stream>>>(x, ao01, ao01 + (size_t)M * D, wo_b,
                                          ln1g, ln1b, hb);

  gemm256<2, 1><<<dim3(F / 256, M / 256), 512, 0, stream>>>(hb, w1b, gb, b1, M, F, D);

  // FFN2: 256^2 8-phase, K-split x4 -> fb[0..3] (b2 folded into ln2)
  gemm256<0, 4><<<dim3(D / 256, (M / 256) * 4), 512, 0, stream>>>(gb, w2b, fb, nullptr, M, D, F);

  ln2_kernel<<<dim3(M), 256, 0, stream>>>(hb, fb, (size_t)M * D, b2,
                                          ln2g, ln2b, out);
}